// Round 2
// baseline (712.707 us; speedup 1.0000x reference)
//
#include <hip/hip_runtime.h>
#include <math.h>

// Problem constants (fixed by setup_inputs)
constexpr int Bc  = 32;     // batch
constexpr int Dc  = 256;    // word feature dim
constexpr int Tc  = 32;     // seq len
constexpr int DHc = 128;    // image feature dim
constexpr int Nc  = 16384;  // H*W = 128*128

// Stage 1: values[b,k,t] = bias[k] + sum_d W[k,d] * wf[b,d,t]
__global__ __launch_bounds__(256) void values_kernel(
    const float* __restrict__ wf, const float* __restrict__ Wm,
    const float* __restrict__ bias, float* __restrict__ values)
{
    int id = blockIdx.x * 256 + threadIdx.x;    // 131072 total
    int t = id & (Tc - 1);
    int k = (id >> 5) & (DHc - 1);
    int b = id >> 12;
    const float* wrow = Wm + (size_t)k * Dc;
    const float* wfp  = wf + (size_t)b * Dc * Tc + t;
    float acc = bias[k];
    #pragma unroll 8
    for (int d = 0; d < Dc; ++d)
        acc = fmaf(wrow[d], wfp[(size_t)d * Tc], acc);
    values[id] = acc;   // layout [b][k][t] contiguous
}

// Stage 2: per 512-pixel tile of one batch. V rows are read with wave-uniform
// addresses straight from global -> compiler promotes to scalar loads (SGPRs),
// freeing the LDS and VMEM pipes. q loads are double-buffered 4 deep.
__global__ __launch_bounds__(256, 4) void attn_kernel(
    const float* __restrict__ img, const float* __restrict__ values,
    const int* __restrict__ mask, float* __restrict__ attn,
    float* __restrict__ coeff)
{
    const int tid  = threadIdx.x;
    const int b    = blockIdx.x >> 5;    // 32 tiles per batch
    const int tile = blockIdx.x & 31;
    const int n    = tile * 512 + tid * 2;          // this thread's pixel pair

    const float* __restrict__ vb = values + (size_t)b * DHc * Tc;  // uniform base
    const float* __restrict__ qp = img + (size_t)b * DHc * Nc + n;

    // words mask -> single uniform bitmask (1 SGPR)
    unsigned mbits = 0u;
    #pragma unroll
    for (int t = 0; t < Tc; ++t)
        mbits |= mask[b * Tc + t] ? (1u << t) : 0u;

    float s0[Tc], s1[Tc];
    #pragma unroll
    for (int t = 0; t < Tc; ++t) { s0[t] = 0.0f; s1[t] = 0.0f; }

    // ---- QK^T : S[n,t] = sum_k q[k]*V[k,t], chunk-of-4 double-buffered ----
    float2 qA[4], qB[4];
    #pragma unroll
    for (int j = 0; j < 4; ++j) qA[j] = *(const float2*)(qp + (size_t)j * Nc);

    for (int c = 0; c < 32; c += 2) {
        // prefetch chunk c+1
        #pragma unroll
        for (int j = 0; j < 4; ++j)
            qB[j] = *(const float2*)(qp + (size_t)((c + 1) * 4 + j) * Nc);
        // compute chunk c
        #pragma unroll
        for (int j = 0; j < 4; ++j) {
            const int k = c * 4 + j;
            const float2 q = qA[j];
            const float* vr = vb + k * Tc;           // wave-uniform
            #pragma unroll
            for (int t = 0; t < Tc; ++t) {
                const float v = vr[t];               // -> s_load (SGPR)
                s0[t] = fmaf(q.x, v, s0[t]);
                s1[t] = fmaf(q.y, v, s1[t]);
            }
        }
        // prefetch chunk c+2
        if (c + 2 < 32) {
            #pragma unroll
            for (int j = 0; j < 4; ++j)
                qA[j] = *(const float2*)(qp + (size_t)((c + 2) * 4 + j) * Nc);
        }
        // compute chunk c+1
        #pragma unroll
        for (int j = 0; j < 4; ++j) {
            const int k = (c + 1) * 4 + j;
            const float2 q = qB[j];
            const float* vr = vb + k * Tc;
            #pragma unroll
            for (int t = 0; t < Tc; ++t) {
                const float v = vr[t];
                s0[t] = fmaf(q.x, v, s0[t]);
                s1[t] = fmaf(q.y, v, s1[t]);
            }
        }
    }

    // ---- masked softmax over t (registers only) ----
    #pragma unroll
    for (int t = 0; t < Tc; ++t)
        if (mbits & (1u << t)) { s0[t] = -INFINITY; s1[t] = -INFINITY; }

    float m0 = -INFINITY, m1 = -INFINITY;
    #pragma unroll
    for (int t = 0; t < Tc; ++t) { m0 = fmaxf(m0, s0[t]); m1 = fmaxf(m1, s1[t]); }
    float sum0 = 0.0f, sum1 = 0.0f;
    #pragma unroll
    for (int t = 0; t < Tc; ++t) {
        s0[t] = __expf(s0[t] - m0); sum0 += s0[t];
        s1[t] = __expf(s1[t] - m1); sum1 += s1[t];
    }
    const float inv0 = 1.0f / sum0, inv1 = 1.0f / sum1;
    #pragma unroll
    for (int t = 0; t < Tc; ++t) { s0[t] *= inv0; s1[t] *= inv1; }

    // ---- write coefficients [B,N,T]: 64 contiguous floats per thread ----
    {
        float4* cp = (float4*)(coeff + ((size_t)b * Nc + n) * Tc);
        #pragma unroll
        for (int tt = 0; tt < 8; ++tt)
            cp[tt] = make_float4(s0[4*tt+0], s0[4*tt+1], s0[4*tt+2], s0[4*tt+3]);
        #pragma unroll
        for (int tt = 0; tt < 8; ++tt)
            cp[8+tt] = make_float4(s1[4*tt+0], s1[4*tt+1], s1[4*tt+2], s1[4*tt+3]);
    }

    // ---- P·V^T : attn[k,n] = sum_t V[k,t] * p[n,t] ----
    float* ap = attn + (size_t)b * DHc * Nc + n;
    #pragma unroll 2
    for (int k = 0; k < DHc; ++k) {
        const float* vr = vb + k * Tc;               // wave-uniform -> SGPRs
        float a0 = 0.f, b0 = 0.f, c0 = 0.f, d0 = 0.f;
        float a1 = 0.f, b1 = 0.f, c1 = 0.f, d1 = 0.f;
        #pragma unroll
        for (int tt = 0; tt < 8; ++tt) {
            const float vx = vr[4*tt+0], vy = vr[4*tt+1];
            const float vz = vr[4*tt+2], vw = vr[4*tt+3];
            a0 = fmaf(vx, s0[4*tt+0], a0);
            b0 = fmaf(vy, s0[4*tt+1], b0);
            c0 = fmaf(vz, s0[4*tt+2], c0);
            d0 = fmaf(vw, s0[4*tt+3], d0);
            a1 = fmaf(vx, s1[4*tt+0], a1);
            b1 = fmaf(vy, s1[4*tt+1], b1);
            c1 = fmaf(vz, s1[4*tt+2], c1);
            d1 = fmaf(vw, s1[4*tt+3], d1);
        }
        *(float2*)(ap + (size_t)k * Nc) =
            make_float2((a0 + b0) + (c0 + d0), (a1 + b1) + (c1 + d1));
    }
}

extern "C" void kernel_launch(void* const* d_in, const int* in_sizes, int n_in,
                              void* d_out, int out_size, void* d_ws, size_t ws_size,
                              hipStream_t stream)
{
    const float* wf   = (const float*)d_in[0];  // [B,D,T]
    const float* img  = (const float*)d_in[1];  // [B,Dh,H,W]
    const int*   msk  = (const int*)d_in[2];    // [B,T]
    const float* Wm   = (const float*)d_in[3];  // [Dh,D]
    const float* bias = (const float*)d_in[4];  // [Dh]

    float* attn  = (float*)d_out;                        // [B,Dh,N]
    float* coeff = attn + (size_t)Bc * DHc * Nc;         // [B,N,T]
    float* vals  = (float*)d_ws;                         // [B,Dh,T] scratch (512 KB)

    values_kernel<<<(Bc * DHc * Tc) / 256, 256, 0, stream>>>(wf, Wm, bias, vals);
    attn_kernel<<<(Bc * Nc) / 512, 256, 0, stream>>>(img, vals, msk, attn, coeff);
}